// Round 4
// baseline (5833.708 us; speedup 1.0000x reference)
//
#include <hip/hip_runtime.h>
#include <stdint.h>

// ---------------- threefry2x32 (exact JAX schedule) ----------------
__host__ __device__ inline void threefry2x32(uint32_t k0, uint32_t k1,
                                             uint32_t x0, uint32_t x1,
                                             uint32_t* o0, uint32_t* o1) {
  uint32_t ks2 = 0x1BD11BDAu ^ k0 ^ k1;
  x0 += k0; x1 += k1;
#define TF_R(x, r) (((x) << (r)) | ((x) >> (32 - (r))))
#define TF_ROUND(r) { x0 += x1; x1 = TF_R(x1, r); x1 ^= x0; }
  TF_ROUND(13) TF_ROUND(15) TF_ROUND(26) TF_ROUND(6)
  x0 += k1; x1 += ks2 + 1u;
  TF_ROUND(17) TF_ROUND(29) TF_ROUND(16) TF_ROUND(24)
  x0 += ks2; x1 += k0 + 2u;
  TF_ROUND(13) TF_ROUND(15) TF_ROUND(26) TF_ROUND(6)
  x0 += k0; x1 += k1 + 3u;
  TF_ROUND(17) TF_ROUND(29) TF_ROUND(16) TF_ROUND(24)
  x0 += k1; x1 += ks2 + 4u;
  TF_ROUND(13) TF_ROUND(15) TF_ROUND(26) TF_ROUND(6)
  x0 += ks2; x1 += k0 + 5u;
  *o0 = x0; *o1 = x1;
#undef TF_ROUND
#undef TF_R
}

__device__ __forceinline__ float wave_sum(float v) {
#pragma unroll
  for (int o = 32; o > 0; o >>= 1) v += __shfl_xor(v, o, 64);
  return v;
}
__device__ __forceinline__ float wave_max(float v) {
#pragma unroll
  for (int o = 32; o > 0; o >>= 1) v = fmaxf(v, __shfl_xor(v, o, 64));
  return v;
}

// ------------- GEMM v2: double-buffered LDS, register prefetch, split-K -----
// out = X @ W^T (+bias if direct).  X rows batch-mapped: m -> (b=m/St, s=m%St).
// partial=1: write raw partial to out[(bz*M + m)*ldo + n]  (bias added later)
__global__ __launch_bounds__(256) void gemm2_kernel(
    const float* __restrict__ X, long long xbs, int ldx,
    const float* __restrict__ W, int ldw,
    const float* __restrict__ bias,
    float* __restrict__ out, long long obs, int ldo,
    int St, int M, int N, int K32, int relu, int partial) {
  __shared__ __align__(16) float Xl[2][32][68];
  __shared__ __align__(16) float Wl[2][32][68];
  const int tid = threadIdx.x;
  const int m0 = blockIdx.x * 64;
  const int n0 = blockIdx.y * 64;
  const long long kbase = (long long)blockIdx.z * K32 * 32;
  const int mi = tid >> 4;       // 0..15
  const int ni = tid & 15;       // 0..15
  const int lr = tid >> 3;       // 0..31
  const int lc = (tid & 7) * 4;  // 0,4,...,28

  const int mA = m0 + lr, mB = m0 + lr + 32;
  const float* xpA = nullptr;
  const float* xpB = nullptr;
  if (mA < M) {
    int b = mA / St, s = mA - b * St;
    xpA = X + (long long)b * xbs + (long long)s * ldx + kbase + lc;
  }
  if (mB < M) {
    int b = mB / St, s = mB - b * St;
    xpB = X + (long long)b * xbs + (long long)s * ldx + kbase + lc;
  }
  const float* wpA = W + (long long)(n0 + lr) * ldw + kbase + lc;
  const float* wpB = W + (long long)(n0 + lr + 32) * ldw + kbase + lc;

  float4 xA = xpA ? *(const float4*)xpA : make_float4(0.f, 0.f, 0.f, 0.f);
  float4 xB = xpB ? *(const float4*)xpB : make_float4(0.f, 0.f, 0.f, 0.f);
  float4 wA = *(const float4*)wpA;
  float4 wB = *(const float4*)wpB;

  float acc[4][4];
#pragma unroll
  for (int i = 0; i < 4; ++i)
#pragma unroll
    for (int j = 0; j < 4; ++j) acc[i][j] = 0.f;

  Xl[0][lc + 0][lr] = xA.x; Xl[0][lc + 1][lr] = xA.y;
  Xl[0][lc + 2][lr] = xA.z; Xl[0][lc + 3][lr] = xA.w;
  Xl[0][lc + 0][lr + 32] = xB.x; Xl[0][lc + 1][lr + 32] = xB.y;
  Xl[0][lc + 2][lr + 32] = xB.z; Xl[0][lc + 3][lr + 32] = xB.w;
  Wl[0][lc + 0][lr] = wA.x; Wl[0][lc + 1][lr] = wA.y;
  Wl[0][lc + 2][lr] = wA.z; Wl[0][lc + 3][lr] = wA.w;
  Wl[0][lc + 0][lr + 32] = wB.x; Wl[0][lc + 1][lr + 32] = wB.y;
  Wl[0][lc + 2][lr + 32] = wB.z; Wl[0][lc + 3][lr + 32] = wB.w;
  __syncthreads();

  for (int i = 0; i < K32; ++i) {
    if (i + 1 < K32) {  // issue next tile's loads BEFORE compute
      int off = (i + 1) * 32;
      xA = xpA ? *(const float4*)(xpA + off) : make_float4(0.f, 0.f, 0.f, 0.f);
      xB = xpB ? *(const float4*)(xpB + off) : make_float4(0.f, 0.f, 0.f, 0.f);
      wA = *(const float4*)(wpA + off);
      wB = *(const float4*)(wpB + off);
    }
    const int cur = i & 1;
#pragma unroll
    for (int kk = 0; kk < 32; ++kk) {
      float4 xv = *(const float4*)&Xl[cur][kk][mi * 4];
      float4 wv = *(const float4*)&Wl[cur][kk][ni * 4];
      float xa[4] = {xv.x, xv.y, xv.z, xv.w};
      float wa[4] = {wv.x, wv.y, wv.z, wv.w};
#pragma unroll
      for (int a = 0; a < 4; ++a)
#pragma unroll
        for (int c = 0; c < 4; ++c) acc[a][c] = fmaf(xa[a], wa[c], acc[a][c]);
    }
    if (i + 1 < K32) {
      __syncthreads();
      const int nxt = cur ^ 1;
      Xl[nxt][lc + 0][lr] = xA.x; Xl[nxt][lc + 1][lr] = xA.y;
      Xl[nxt][lc + 2][lr] = xA.z; Xl[nxt][lc + 3][lr] = xA.w;
      Xl[nxt][lc + 0][lr + 32] = xB.x; Xl[nxt][lc + 1][lr + 32] = xB.y;
      Xl[nxt][lc + 2][lr + 32] = xB.z; Xl[nxt][lc + 3][lr + 32] = xB.w;
      Wl[nxt][lc + 0][lr] = wA.x; Wl[nxt][lc + 1][lr] = wA.y;
      Wl[nxt][lc + 2][lr] = wA.z; Wl[nxt][lc + 3][lr] = wA.w;
      Wl[nxt][lc + 0][lr + 32] = wB.x; Wl[nxt][lc + 1][lr + 32] = wB.y;
      Wl[nxt][lc + 2][lr + 32] = wB.z; Wl[nxt][lc + 3][lr + 32] = wB.w;
      __syncthreads();
    }
  }

  const int n = n0 + ni * 4;
  if (partial) {
    float* base = out + (long long)blockIdx.z * M * ldo;
#pragma unroll
    for (int i = 0; i < 4; ++i) {
      int m = m0 + mi * 4 + i;
      if (m >= M) continue;
      *(float4*)(base + (long long)m * ldo + n) =
          make_float4(acc[i][0], acc[i][1], acc[i][2], acc[i][3]);
    }
  } else {
    float4 bv = *(const float4*)(bias + n);
#pragma unroll
    for (int i = 0; i < 4; ++i) {
      int m = m0 + mi * 4 + i;
      if (m >= M) continue;
      int b = m / St, s = m - b * St;
      float4 o;
      o.x = acc[i][0] + bv.x; o.y = acc[i][1] + bv.y;
      o.z = acc[i][2] + bv.z; o.w = acc[i][3] + bv.w;
      if (relu) {
        o.x = fmaxf(o.x, 0.f); o.y = fmaxf(o.y, 0.f);
        o.z = fmaxf(o.z, 0.f); o.w = fmaxf(o.w, 0.f);
      }
      *(float4*)(out + (long long)b * obs + (long long)s * ldo + n) = o;
    }
  }
}

// ------- epilogue: sum split-K partials + bias (+res) (+relu) (+LayerNorm) --
__global__ __launch_bounds__(256) void epi_kernel(
    const float* __restrict__ P, int splits, int M, int N,
    const float* __restrict__ bias,
    const float* __restrict__ res, long long rbs, int ldr,
    const float* __restrict__ lnw, const float* __restrict__ lnb,
    float* __restrict__ out, long long obs, int ldo, int St, int relu) {
  __shared__ float red[4];
  const int m = blockIdx.x;
  const int b = m / St, s = m - b * St;
  const int n = blockIdx.y * 1024 + threadIdx.x * 4;
  const float* pr = P + (long long)m * N + n;
  float4 v = *(const float4*)pr;
  for (int sp = 1; sp < splits; ++sp) {
    float4 w2 = *(const float4*)(pr + (long long)sp * M * N);
    v.x += w2.x; v.y += w2.y; v.z += w2.z; v.w += w2.w;
  }
  float4 bv = *(const float4*)(bias + n);
  v.x += bv.x; v.y += bv.y; v.z += bv.z; v.w += bv.w;
  if (res) {
    float4 rv = *(const float4*)(res + (long long)b * rbs + (long long)s * ldr + n);
    v.x += rv.x; v.y += rv.y; v.z += rv.z; v.w += rv.w;
  }
  if (relu) {
    v.x = fmaxf(v.x, 0.f); v.y = fmaxf(v.y, 0.f);
    v.z = fmaxf(v.z, 0.f); v.w = fmaxf(v.w, 0.f);
  }
  if (lnw) {
    const int tid = threadIdx.x;
    float sum = wave_sum(v.x + v.y + v.z + v.w);
    int wid = tid >> 6;
    if ((tid & 63) == 0) red[wid] = sum;
    __syncthreads();
    float mean = (red[0] + red[1] + red[2] + red[3]) * (1.f / 1024.f);
    float4 d;
    d.x = v.x - mean; d.y = v.y - mean; d.z = v.z - mean; d.w = v.w - mean;
    float s2 = wave_sum(d.x * d.x + d.y * d.y + d.z * d.z + d.w * d.w);
    __syncthreads();
    if ((tid & 63) == 0) red[wid] = s2;
    __syncthreads();
    float var = (red[0] + red[1] + red[2] + red[3]) * (1.f / 1024.f);
    float inv = rsqrtf(var + 1e-5f);
    float4 wv = *(const float4*)(lnw + tid * 4);
    float4 lb = *(const float4*)(lnb + tid * 4);
    v.x = d.x * inv * wv.x + lb.x;
    v.y = d.y * inv * wv.y + lb.y;
    v.z = d.z * inv * wv.z + lb.z;
    v.w = d.w * inv * wv.w + lb.w;
  }
  *(float4*)(out + (long long)b * obs + (long long)s * ldo + n) = v;
}

// --------- attention: one wave per (b,h,sq); optional Q partial-sum+bias ----
__global__ __launch_bounds__(64) void attn_kernel(
    const float* __restrict__ Qp, int q_rs, long long q_bs,
    const float* __restrict__ Qp2,    // second split-K partial of Q (or null)
    const float* __restrict__ qbias,  // Q bias (1024, or null)
    const float* __restrict__ Kp, int k_rs, long long k_bs,
    const float* __restrict__ Vp, int v_rs, long long v_bs,
    float* __restrict__ Op, int o_rs, long long o_bs,
    int Sq, int Skv) {
  const int lane = threadIdx.x;
  int bid = blockIdx.x;
  int b = bid / (8 * Sq);
  int rr = bid - b * 8 * Sq;
  int h = rr / Sq;
  int sq = rr - h * Sq;
  const float* qrow = Qp + (long long)b * q_bs + (long long)sq * q_rs + h * 128;
  float q0 = qrow[lane], q1 = qrow[lane + 64];
  if (Qp2) {
    const float* q2 = Qp2 + (long long)b * q_bs + (long long)sq * q_rs + h * 128;
    q0 += q2[lane]; q1 += q2[lane + 64];
  }
  if (qbias) {
    q0 += qbias[h * 128 + lane]; q1 += qbias[h * 128 + lane + 64];
  }
  __shared__ float sc[72];
  const float* kb = Kp + (long long)b * k_bs + h * 128;
  for (int sk = 0; sk < Skv; ++sk) {
    const float* kr = kb + (long long)sk * k_rs;
    float p = fmaf(q0, kr[lane], q1 * kr[lane + 64]);
    p = wave_sum(p);
    if (lane == 0) sc[sk] = p * 0.08838834764831845f;  // 1/sqrt(128)
  }
  __syncthreads();
  float m = -3.4e38f;
  for (int i = lane; i < Skv; i += 64) m = fmaxf(m, sc[i]);
  m = wave_max(m);
  float ssum = 0.f;
  for (int i = lane; i < Skv; i += 64) {
    float e = expf(sc[i] - m);
    sc[i] = e;
    ssum += e;
  }
  ssum = wave_sum(ssum);
  __syncthreads();
  float o0 = 0.f, o1 = 0.f;
  const float* vb = Vp + (long long)b * v_bs + h * 128;
  for (int sk = 0; sk < Skv; ++sk) {
    float w = sc[sk];
    const float* vr = vb + (long long)sk * v_rs;
    o0 = fmaf(w, vr[lane], o0);
    o1 = fmaf(w, vr[lane + 64], o1);
  }
  float inv = 1.f / ssum;
  float* orow = Op + (long long)b * o_bs + (long long)sq * o_rs + h * 128;
  orow[lane] = o0 * inv;
  orow[lane + 64] = o1 * inv;
}

// ---------------- small preprocessing kernels ----------------
__global__ __launch_bounds__(256) void copy_cur_kernel(
    const float* __restrict__ emb, float* __restrict__ cur) {
  int idx = blockIdx.x * 256 + threadIdx.x;
  int b = idx >> 16;
  int r = idx & 65535;
  cur[(long long)b * 73728 + r] = emb[idx];
}

__global__ __launch_bounds__(256) void xmean_kernel(
    const float* __restrict__ emb, float* __restrict__ xmean) {
  int idx = blockIdx.x * 256 + threadIdx.x;
  int b = idx >> 10, d = idx & 1023;
  float s = 0.f;
  for (int ss = 0; ss < 64; ++ss) s += emb[b * 65536 + ss * 1024 + d];
  xmean[idx] = s * (1.f / 64.f);
}

__global__ __launch_bounds__(256) void temp_kernel(
    const float* __restrict__ emb, const float* __restrict__ tw,
    const float* __restrict__ tb, float* __restrict__ tempv) {
  __shared__ float red[4];
  int b = blockIdx.x;
  int wid = threadIdx.x >> 6, lane = threadIdx.x & 63;
  float acc = 0.f;
  for (int s = wid; s < 64; s += 4) {
    const float* x = emb + b * 65536 + s * 1024;
    float p = 0.f;
#pragma unroll
    for (int it = 0; it < 4; ++it) {
      float4 xv = *(const float4*)(x + it * 256 + lane * 4);
      float4 wv = *(const float4*)(tw + it * 256 + lane * 4);
      p += xv.x * wv.x + xv.y * wv.y + xv.z * wv.z + xv.w * wv.w;
    }
    p = wave_sum(p);
    acc += 1.f / (1.f + expf(-(p + tb[0])));
  }
  if (lane == 0) red[wid] = acc;
  __syncthreads();
  if (threadIdx.x == 0)
    tempv[b] = (red[0] + red[1] + red[2] + red[3]) * (1.f / 64.f);
}

__global__ __launch_bounds__(256) void style_kernel(
    const float* __restrict__ xmean, const float* __restrict__ sw,
    const float* __restrict__ sb, float* __restrict__ stylev) {
  int wid = threadIdx.x >> 6, lane = threadIdx.x & 63;
  int d = blockIdx.x * 4 + wid;
  const float* wr = sw + (long long)d * 1024;
  float a0 = 0.f, a1 = 0.f;
#pragma unroll
  for (int it = 0; it < 4; ++it) {
    float4 wv = *(const float4*)(wr + it * 256 + lane * 4);
    float4 x0 = *(const float4*)(xmean + it * 256 + lane * 4);
    float4 x1 = *(const float4*)(xmean + 1024 + it * 256 + lane * 4);
    a0 += wv.x * x0.x + wv.y * x0.y + wv.z * x0.z + wv.w * x0.w;
    a1 += wv.x * x1.x + wv.y * x1.y + wv.z * x1.z + wv.w * x1.w;
  }
  a0 = wave_sum(a0);
  a1 = wave_sum(a1);
  if (lane == 0) {
    stylev[d] = a0 + sb[d];
    stylev[1024 + d] = a1 + sb[d];
  }
}

// -------- logits (z computed inline): one wave per vocab row ----------
__global__ __launch_bounds__(256) void logits_kernel(
    const float* __restrict__ A, const float* __restrict__ stylev, int St,
    const float* __restrict__ Wo, const float* __restrict__ bo,
    const float* __restrict__ tempv, float* __restrict__ outl, int t) {
  int wid = threadIdx.x >> 6, lane = threadIdx.x & 63;
  int n = blockIdx.x * 4 + wid;
  const float* wr = Wo + (long long)n * 1024;
  const float* a0p = A + (long long)(St - 1) * 1024;
  const float* a1p = A + 73728 + (long long)(St - 1) * 1024;
  float a0 = 0.f, a1 = 0.f;
#pragma unroll
  for (int it = 0; it < 4; ++it) {
    int off = it * 256 + lane * 4;
    float4 wv = *(const float4*)(wr + off);
    float4 x0 = *(const float4*)(a0p + off);
    float4 s0 = *(const float4*)(stylev + off);
    float4 x1 = *(const float4*)(a1p + off);
    float4 s1 = *(const float4*)(stylev + 1024 + off);
    float4 z0 = make_float4(x0.x + s0.x, x0.y + s0.y, x0.z + s0.z, x0.w + s0.w);
    float4 z1 = make_float4(x1.x + s1.x, x1.y + s1.y, x1.z + s1.z, x1.w + s1.w);
    a0 += wv.x * z0.x + wv.y * z0.y + wv.z * z0.z + wv.w * z0.w;
    a1 += wv.x * z1.x + wv.y * z1.y + wv.z * z1.z + wv.w * z1.w;
  }
  a0 = wave_sum(a0);
  a1 = wave_sum(a1);
  if (lane == 0) {
    float bb = bo[n];
    outl[(long long)(0 * 8 + t) * 32000 + n] = (a0 + bb) / tempv[0];
    outl[(long long)(1 * 8 + t) * 32000 + n] = (a1 + bb) / tempv[1];
  }
}

// -------- Gumbel argmax sampling (partitionable threefry) + append ---------
__global__ __launch_bounds__(1024) void sample_kernel(
    const float* __restrict__ logits, const float* __restrict__ Wo,
    float* __restrict__ tok_f, float* __restrict__ cur, int St,
    uint32_t fk0, uint32_t fk1, int t) {
  int b = blockIdx.x;
  const float* lg = logits + (long long)(b * 8 + t) * 32000;
  float best = -3.4e38f;
  int bi = 0x7fffffff;
  for (int n = threadIdx.x; n < 32000; n += 1024) {
    uint32_t r0, r1;
    threefry2x32(fk0, fk1, 0u, (uint32_t)(b * 32000 + n), &r0, &r1);
    uint32_t bits = (r0 ^ r1) >> 9;
    float u = __uint_as_float(0x3f800000u | bits) - 1.0f;
    if (u < 1.1754944e-38f) u = 1.1754944e-38f;
    float g = -logf(-logf(u));
    float val = lg[n] + g;
    if (val > best) { best = val; bi = n; }
  }
  __shared__ float bv[1024];
  __shared__ int bix[1024];
  bv[threadIdx.x] = best;
  bix[threadIdx.x] = bi;
  __syncthreads();
  for (int s = 512; s > 0; s >>= 1) {
    if (threadIdx.x < s) {
      float ov = bv[threadIdx.x + s];
      int oi = bix[threadIdx.x + s];
      if (ov > bv[threadIdx.x] ||
          (ov == bv[threadIdx.x] && oi < bix[threadIdx.x])) {
        bv[threadIdx.x] = ov;
        bix[threadIdx.x] = oi;
      }
    }
    __syncthreads();
  }
  int tok = bix[0];
  if (threadIdx.x == 0) tok_f[b * 8 + t] = (float)tok;
  // fused append: re-embed token via out_w row
  cur[(long long)b * 73728 + (long long)St * 1024 + threadIdx.x] =
      Wo[(long long)tok * 1024 + threadIdx.x];
}

// ---------------- host helpers ----------------
static inline void g2(hipStream_t st, const float* X, long long xbs, int ldx,
                      const float* W, int ldw, const float* bias, float* out,
                      long long obs, int ldo, int St, int M, int N, int K,
                      int splits, int relu, int partial) {
  dim3 grid((unsigned)((M + 63) / 64), (unsigned)(N / 64), (unsigned)splits);
  gemm2_kernel<<<grid, 256, 0, st>>>(X, xbs, ldx, W, ldw, bias, out, obs, ldo,
                                     St, M, N, K / (32 * splits), relu,
                                     partial);
}

static inline void epi(hipStream_t st, const float* P, int splits, int M,
                       int N, const float* bias, const float* res,
                       long long rbs, int ldr, const float* lnw,
                       const float* lnb, float* out, long long obs, int ldo,
                       int St, int relu) {
  dim3 grid((unsigned)M, (unsigned)(N / 1024));
  epi_kernel<<<grid, 256, 0, st>>>(P, splits, M, N, bias, res, rbs, ldr, lnw,
                                   lnb, out, obs, ldo, St, relu);
}

extern "C" void kernel_launch(void* const* d_in, const int* in_sizes, int n_in,
                              void* d_out, int out_size, void* d_ws,
                              size_t ws_size, hipStream_t stream) {
  const float* emb = (const float*)d_in[0];
  const float* sa_in_w = (const float*)d_in[1];
  const float* sa_in_b = (const float*)d_in[2];
  const float* sa_out_w = (const float*)d_in[3];
  const float* sa_out_b = (const float*)d_in[4];
  const float* ca_in_w = (const float*)d_in[5];
  const float* ca_in_b = (const float*)d_in[6];
  const float* ca_out_w = (const float*)d_in[7];
  const float* ca_out_b = (const float*)d_in[8];
  const float* ff1_w = (const float*)d_in[9];
  const float* ff1_b = (const float*)d_in[10];
  const float* ff2_w = (const float*)d_in[11];
  const float* ff2_b = (const float*)d_in[12];
  const float* ln_w = (const float*)d_in[13];
  const float* ln_b = (const float*)d_in[14];
  const float* out_w = (const float*)d_in[15];
  const float* out_b = (const float*)d_in[16];
  const float* temp_w = (const float*)d_in[17];
  const float* temp_b = (const float*)d_in[18];
  const float* style_w = (const float*)d_in[21];
  const float* style_b = (const float*)d_in[22];

  float* ws = (float*)d_ws;
  float* cur = ws;                       // [2][72][1024]
  float* A = cur + 2 * 72 * 1024;        // [2][72][1024]
  float* Qb = A + 2 * 72 * 1024;         // [2][72][3072]
  float* Tb = Qb + 2 * 72 * 3072;        // [2][72][1024]
  float* Fb = Tb + 2 * 72 * 1024;        // [2][72][4096]
  float* cakv = Fb + 2 * 72 * 4096;      // [2][2][64][2048]
  float* Pp = cakv + 2 * 2 * 64 * 2048;  // split-K partials
  float* xmean = Pp + 1310720;
  float* stylev = xmean + 2048;
  float* tempv = stylev + 2048;

  float* toks_out = (float*)d_out;
  float* logits_out = toks_out + 16;

  // ---- precompute ----
  copy_cur_kernel<<<512, 256, 0, stream>>>(emb, cur);
  xmean_kernel<<<8, 256, 0, stream>>>(emb, xmean);
  temp_kernel<<<2, 256, 0, stream>>>(emb, temp_w, temp_b, tempv);
  style_kernel<<<256, 256, 0, stream>>>(xmean, style_w, style_b, stylev);
  for (int l = 0; l < 2; ++l) {  // cross-attn K,V (memory is constant)
    g2(stream, emb, 64 * 1024, 1024,
       ca_in_w + (size_t)(l * 3072 + 1024) * 1024, 1024,
       ca_in_b + l * 3072 + 1024, cakv + (size_t)l * 2 * 64 * 2048, 64 * 2048,
       2048, 64, 128, 2048, 1024, 1, 0, 0);
  }

  for (int t = 0; t < 8; ++t) {
    int St = 64 + t;
    int M = 2 * St;
    for (int l = 0; l < 2; ++l) {
      const float* P0 = (l == 0) ? cur : A;
      // self-attn QKV: direct write with bias (no epi node)
      g2(stream, P0, 72 * 1024, 1024, sa_in_w + (size_t)l * 3072 * 1024, 1024,
         sa_in_b + l * 3072, Qb, 72 * 3072, 3072, St, M, 3072, 1024, 1, 0, 0);
      attn_kernel<<<2 * 8 * St, 64, 0, stream>>>(
          Qb, 3072, 72 * 3072, nullptr, nullptr, Qb + 1024, 3072, 72 * 3072,
          Qb + 2048, 3072, 72 * 3072, Tb, 1024, 72 * 1024, St, St);
      // out-proj (split-K x4 -> epi bias+res+LN0)
      g2(stream, Tb, 72 * 1024, 1024, sa_out_w + (size_t)l * 1024 * 1024, 1024,
         nullptr, Pp, 0, 1024, St, M, 1024, 1024, 4, 0, 1);
      epi(stream, Pp, 4, M, 1024, sa_out_b + l * 1024, P0, 72 * 1024, 1024,
          ln_w + (l * 3 + 0) * 1024, ln_b + (l * 3 + 0) * 1024, A, 72 * 1024,
          1024, St, 0);
      // cross-attn Q (split-K x2, partials summed inside attn)
      g2(stream, A, 72 * 1024, 1024, ca_in_w + (size_t)l * 3072 * 1024, 1024,
         nullptr, Pp, 0, 1024, St, M, 1024, 1024, 2, 0, 1);
      attn_kernel<<<2 * 8 * St, 64, 0, stream>>>(
          Pp, 1024, (long long)St * 1024, Pp + (size_t)M * 1024,
          ca_in_b + l * 3072, cakv + (size_t)l * 2 * 64 * 2048, 2048,
          64 * 2048, cakv + (size_t)l * 2 * 64 * 2048 + 1024, 2048, 64 * 2048,
          Tb, 1024, 72 * 1024, St, 64);
      // ca out-proj (split-K x4 -> epi bias+res+LN1)
      g2(stream, Tb, 72 * 1024, 1024, ca_out_w + (size_t)l * 1024 * 1024, 1024,
         nullptr, Pp, 0, 1024, St, M, 1024, 1024, 4, 0, 1);
      epi(stream, Pp, 4, M, 1024, ca_out_b + l * 1024, A, 72 * 1024, 1024,
          ln_w + (l * 3 + 1) * 1024, ln_b + (l * 3 + 1) * 1024, A, 72 * 1024,
          1024, St, 0);
      // FFN1: direct write with bias+relu (no epi node)
      g2(stream, A, 72 * 1024, 1024, ff1_w + (size_t)l * 4096 * 1024, 1024,
         ff1_b + l * 4096, Fb, 72 * 4096, 4096, St, M, 4096, 1024, 1, 1, 0);
      // FFN2 (split-K x8 -> epi bias+res+LN2)
      g2(stream, Fb, 72 * 4096, 4096, ff2_w + (size_t)l * 1024 * 4096, 4096,
         nullptr, Pp, 0, 1024, St, M, 1024, 4096, 8, 0, 1);
      epi(stream, Pp, 8, M, 1024, ff2_b + l * 1024, A, 72 * 1024, 1024,
          ln_w + (l * 3 + 2) * 1024, ln_b + (l * 3 + 2) * 1024, A, 72 * 1024,
          1024, St, 0);
    }
    logits_kernel<<<8000, 256, 0, stream>>>(A, stylev, St, out_w, out_b,
                                            tempv, logits_out, t);
    uint32_t fk0, fk1;
    threefry2x32(0u, 42u, 0u, (uint32_t)t, &fk0, &fk1);
    sample_kernel<<<2, 1024, 0, stream>>>(logits_out, out_w, toks_out, cur,
                                          St, fk0, fk1, t);
  }
}

// Round 5
// 5164.844 us; speedup vs baseline: 1.1295x; 1.1295x over previous
//
#include <hip/hip_runtime.h>
#include <stdint.h>

// ---------------- threefry2x32 (exact JAX schedule) ----------------
__host__ __device__ inline void threefry2x32(uint32_t k0, uint32_t k1,
                                             uint32_t x0, uint32_t x1,
                                             uint32_t* o0, uint32_t* o1) {
  uint32_t ks2 = 0x1BD11BDAu ^ k0 ^ k1;
  x0 += k0; x1 += k1;
#define TF_R(x, r) (((x) << (r)) | ((x) >> (32 - (r))))
#define TF_ROUND(r) { x0 += x1; x1 = TF_R(x1, r); x1 ^= x0; }
  TF_ROUND(13) TF_ROUND(15) TF_ROUND(26) TF_ROUND(6)
  x0 += k1; x1 += ks2 + 1u;
  TF_ROUND(17) TF_ROUND(29) TF_ROUND(16) TF_ROUND(24)
  x0 += ks2; x1 += k0 + 2u;
  TF_ROUND(13) TF_ROUND(15) TF_ROUND(26) TF_ROUND(6)
  x0 += k0; x1 += k1 + 3u;
  TF_ROUND(17) TF_ROUND(29) TF_ROUND(16) TF_ROUND(24)
  x0 += k1; x1 += ks2 + 4u;
  TF_ROUND(13) TF_ROUND(15) TF_ROUND(26) TF_ROUND(6)
  x0 += ks2; x1 += k0 + 5u;
  *o0 = x0; *o1 = x1;
#undef TF_ROUND
#undef TF_R
}

__device__ __forceinline__ float wave_sum(float v) {
#pragma unroll
  for (int o = 32; o > 0; o >>= 1) v += __shfl_xor(v, o, 64);
  return v;
}
__device__ __forceinline__ float wave_max(float v) {
#pragma unroll
  for (int o = 32; o > 0; o >>= 1) v = fmaxf(v, __shfl_xor(v, o, 64));
  return v;
}

// ------------- GEMM v2: double-buffered LDS, register prefetch, split-K -----
// out = X @ W^T (+bias if direct).  X rows batch-mapped: m -> (b=m/St, s=m%St).
// partial=1: write raw partial to out[(bz*M + m)*ldo + n]  (bias added later)
__global__ __launch_bounds__(256) void gemm2_kernel(
    const float* __restrict__ X, long long xbs, int ldx,
    const float* __restrict__ W, int ldw,
    const float* __restrict__ bias,
    float* __restrict__ out, long long obs, int ldo,
    int St, int M, int N, int K32, int relu, int partial) {
  __shared__ __align__(16) float Xl[2][32][68];
  __shared__ __align__(16) float Wl[2][32][68];
  const int tid = threadIdx.x;
  const int m0 = blockIdx.x * 64;
  const int n0 = blockIdx.y * 64;
  const long long kbase = (long long)blockIdx.z * K32 * 32;
  const int mi = tid >> 4;       // 0..15
  const int ni = tid & 15;       // 0..15
  const int lr = tid >> 3;       // 0..31
  const int lc = (tid & 7) * 4;  // 0,4,...,28

  const int mA = m0 + lr, mB = m0 + lr + 32;
  const float* xpA = nullptr;
  const float* xpB = nullptr;
  if (mA < M) {
    int b = mA / St, s = mA - b * St;
    xpA = X + (long long)b * xbs + (long long)s * ldx + kbase + lc;
  }
  if (mB < M) {
    int b = mB / St, s = mB - b * St;
    xpB = X + (long long)b * xbs + (long long)s * ldx + kbase + lc;
  }
  const float* wpA = W + (long long)(n0 + lr) * ldw + kbase + lc;
  const float* wpB = W + (long long)(n0 + lr + 32) * ldw + kbase + lc;

  float4 xA = xpA ? *(const float4*)xpA : make_float4(0.f, 0.f, 0.f, 0.f);
  float4 xB = xpB ? *(const float4*)xpB : make_float4(0.f, 0.f, 0.f, 0.f);
  float4 wA = *(const float4*)wpA;
  float4 wB = *(const float4*)wpB;

  float acc[4][4];
#pragma unroll
  for (int i = 0; i < 4; ++i)
#pragma unroll
    for (int j = 0; j < 4; ++j) acc[i][j] = 0.f;

  Xl[0][lc + 0][lr] = xA.x; Xl[0][lc + 1][lr] = xA.y;
  Xl[0][lc + 2][lr] = xA.z; Xl[0][lc + 3][lr] = xA.w;
  Xl[0][lc + 0][lr + 32] = xB.x; Xl[0][lc + 1][lr + 32] = xB.y;
  Xl[0][lc + 2][lr + 32] = xB.z; Xl[0][lc + 3][lr + 32] = xB.w;
  Wl[0][lc + 0][lr] = wA.x; Wl[0][lc + 1][lr] = wA.y;
  Wl[0][lc + 2][lr] = wA.z; Wl[0][lc + 3][lr] = wA.w;
  Wl[0][lc + 0][lr + 32] = wB.x; Wl[0][lc + 1][lr + 32] = wB.y;
  Wl[0][lc + 2][lr + 32] = wB.z; Wl[0][lc + 3][lr + 32] = wB.w;
  __syncthreads();

  for (int i = 0; i < K32; ++i) {
    if (i + 1 < K32) {  // issue next tile's loads BEFORE compute
      int off = (i + 1) * 32;
      xA = xpA ? *(const float4*)(xpA + off) : make_float4(0.f, 0.f, 0.f, 0.f);
      xB = xpB ? *(const float4*)(xpB + off) : make_float4(0.f, 0.f, 0.f, 0.f);
      wA = *(const float4*)(wpA + off);
      wB = *(const float4*)(wpB + off);
    }
    const int cur = i & 1;
#pragma unroll
    for (int kk = 0; kk < 32; ++kk) {
      float4 xv = *(const float4*)&Xl[cur][kk][mi * 4];
      float4 wv = *(const float4*)&Wl[cur][kk][ni * 4];
      float xa[4] = {xv.x, xv.y, xv.z, xv.w};
      float wa[4] = {wv.x, wv.y, wv.z, wv.w};
#pragma unroll
      for (int a = 0; a < 4; ++a)
#pragma unroll
        for (int c = 0; c < 4; ++c) acc[a][c] = fmaf(xa[a], wa[c], acc[a][c]);
    }
    if (i + 1 < K32) {
      __syncthreads();
      const int nxt = cur ^ 1;
      Xl[nxt][lc + 0][lr] = xA.x; Xl[nxt][lc + 1][lr] = xA.y;
      Xl[nxt][lc + 2][lr] = xA.z; Xl[nxt][lc + 3][lr] = xA.w;
      Xl[nxt][lc + 0][lr + 32] = xB.x; Xl[nxt][lc + 1][lr + 32] = xB.y;
      Xl[nxt][lc + 2][lr + 32] = xB.z; Xl[nxt][lc + 3][lr + 32] = xB.w;
      Wl[nxt][lc + 0][lr] = wA.x; Wl[nxt][lc + 1][lr] = wA.y;
      Wl[nxt][lc + 2][lr] = wA.z; Wl[nxt][lc + 3][lr] = wA.w;
      Wl[nxt][lc + 0][lr + 32] = wB.x; Wl[nxt][lc + 1][lr + 32] = wB.y;
      Wl[nxt][lc + 2][lr + 32] = wB.z; Wl[nxt][lc + 3][lr + 32] = wB.w;
      __syncthreads();
    }
  }

  const int n = n0 + ni * 4;
  if (partial) {
    float* base = out + (long long)blockIdx.z * M * ldo;
#pragma unroll
    for (int i = 0; i < 4; ++i) {
      int m = m0 + mi * 4 + i;
      if (m >= M) continue;
      *(float4*)(base + (long long)m * ldo + n) =
          make_float4(acc[i][0], acc[i][1], acc[i][2], acc[i][3]);
    }
  } else {
    float4 bv = *(const float4*)(bias + n);
#pragma unroll
    for (int i = 0; i < 4; ++i) {
      int m = m0 + mi * 4 + i;
      if (m >= M) continue;
      int b = m / St, s = m - b * St;
      float4 o;
      o.x = acc[i][0] + bv.x; o.y = acc[i][1] + bv.y;
      o.z = acc[i][2] + bv.z; o.w = acc[i][3] + bv.w;
      if (relu) {
        o.x = fmaxf(o.x, 0.f); o.y = fmaxf(o.y, 0.f);
        o.z = fmaxf(o.z, 0.f); o.w = fmaxf(o.w, 0.f);
      }
      *(float4*)(out + (long long)b * obs + (long long)s * ldo + n) = o;
    }
  }
}

// ------- epilogue: sum split-K partials + bias (+res) (+relu) (+LayerNorm) --
__global__ __launch_bounds__(256) void epi_kernel(
    const float* __restrict__ P, int splits, int M, int N,
    const float* __restrict__ bias,
    const float* __restrict__ res, long long rbs, int ldr,
    const float* __restrict__ lnw, const float* __restrict__ lnb,
    float* __restrict__ out, long long obs, int ldo, int St, int relu) {
  __shared__ float red[4];
  const int m = blockIdx.x;
  const int b = m / St, s = m - b * St;
  const int n = blockIdx.y * 1024 + threadIdx.x * 4;
  const float* pr = P + (long long)m * N + n;
  float4 v = *(const float4*)pr;
  for (int sp = 1; sp < splits; ++sp) {
    float4 w2 = *(const float4*)(pr + (long long)sp * M * N);
    v.x += w2.x; v.y += w2.y; v.z += w2.z; v.w += w2.w;
  }
  float4 bv = *(const float4*)(bias + n);
  v.x += bv.x; v.y += bv.y; v.z += bv.z; v.w += bv.w;
  if (res) {
    float4 rv = *(const float4*)(res + (long long)b * rbs + (long long)s * ldr + n);
    v.x += rv.x; v.y += rv.y; v.z += rv.z; v.w += rv.w;
  }
  if (relu) {
    v.x = fmaxf(v.x, 0.f); v.y = fmaxf(v.y, 0.f);
    v.z = fmaxf(v.z, 0.f); v.w = fmaxf(v.w, 0.f);
  }
  if (lnw) {
    const int tid = threadIdx.x;
    float sum = wave_sum(v.x + v.y + v.z + v.w);
    int wid = tid >> 6;
    if ((tid & 63) == 0) red[wid] = sum;
    __syncthreads();
    float mean = (red[0] + red[1] + red[2] + red[3]) * (1.f / 1024.f);
    float4 d;
    d.x = v.x - mean; d.y = v.y - mean; d.z = v.z - mean; d.w = v.w - mean;
    float s2 = wave_sum(d.x * d.x + d.y * d.y + d.z * d.z + d.w * d.w);
    __syncthreads();
    if ((tid & 63) == 0) red[wid] = s2;
    __syncthreads();
    float var = (red[0] + red[1] + red[2] + red[3]) * (1.f / 1024.f);
    float inv = rsqrtf(var + 1e-5f);
    float4 wv = *(const float4*)(lnw + tid * 4);
    float4 lb = *(const float4*)(lnb + tid * 4);
    v.x = d.x * inv * wv.x + lb.x;
    v.y = d.y * inv * wv.y + lb.y;
    v.z = d.z * inv * wv.z + lb.z;
    v.w = d.w * inv * wv.w + lb.w;
  }
  *(float4*)(out + (long long)b * obs + (long long)s * ldo + n) = v;
}

// --------- attention: one wave per (b,h,sq); optional Q partial-sum+bias ----
__global__ __launch_bounds__(64) void attn_kernel(
    const float* __restrict__ Qp, int q_rs, long long q_bs,
    long long q_pstride, int q_nsplit,  // split-K partials of Q
    const float* __restrict__ qbias,    // Q bias (1024, or null)
    const float* __restrict__ Kp, int k_rs, long long k_bs,
    const float* __restrict__ Vp, int v_rs, long long v_bs,
    float* __restrict__ Op, int o_rs, long long o_bs,
    int Sq, int Skv) {
  const int lane = threadIdx.x;
  int bid = blockIdx.x;
  int b = bid / (8 * Sq);
  int rr = bid - b * 8 * Sq;
  int h = rr / Sq;
  int sq = rr - h * Sq;
  const float* qrow = Qp + (long long)b * q_bs + (long long)sq * q_rs + h * 128;
  float q0 = qrow[lane], q1 = qrow[lane + 64];
  for (int sp = 1; sp < q_nsplit; ++sp) {
    const float* q2 = qrow + sp * q_pstride;
    q0 += q2[lane]; q1 += q2[lane + 64];
  }
  if (qbias) {
    q0 += qbias[h * 128 + lane]; q1 += qbias[h * 128 + lane + 64];
  }
  __shared__ float sc[72];
  const float* kb = Kp + (long long)b * k_bs + h * 128;
  for (int sk = 0; sk < Skv; ++sk) {
    const float* kr = kb + (long long)sk * k_rs;
    float p = fmaf(q0, kr[lane], q1 * kr[lane + 64]);
    p = wave_sum(p);
    if (lane == 0) sc[sk] = p * 0.08838834764831845f;  // 1/sqrt(128)
  }
  __syncthreads();
  float m = -3.4e38f;
  for (int i = lane; i < Skv; i += 64) m = fmaxf(m, sc[i]);
  m = wave_max(m);
  float ssum = 0.f;
  for (int i = lane; i < Skv; i += 64) {
    float e = expf(sc[i] - m);
    sc[i] = e;
    ssum += e;
  }
  ssum = wave_sum(ssum);
  __syncthreads();
  float o0 = 0.f, o1 = 0.f;
  const float* vb = Vp + (long long)b * v_bs + h * 128;
  for (int sk = 0; sk < Skv; ++sk) {
    float w = sc[sk];
    const float* vr = vb + (long long)sk * v_rs;
    o0 = fmaf(w, vr[lane], o0);
    o1 = fmaf(w, vr[lane + 64], o1);
  }
  float inv = 1.f / ssum;
  float* orow = Op + (long long)b * o_bs + (long long)sq * o_rs + h * 128;
  orow[lane] = o0 * inv;
  orow[lane + 64] = o1 * inv;
}

// ---------------- small preprocessing kernels ----------------
__global__ __launch_bounds__(256) void copy_cur_kernel(
    const float* __restrict__ emb, float* __restrict__ cur) {
  int idx = blockIdx.x * 256 + threadIdx.x;
  int b = idx >> 16;
  int r = idx & 65535;
  cur[(long long)b * 73728 + r] = emb[idx];
}

__global__ __launch_bounds__(256) void xmean_kernel(
    const float* __restrict__ emb, float* __restrict__ xmean) {
  int idx = blockIdx.x * 256 + threadIdx.x;
  int b = idx >> 10, d = idx & 1023;
  float s = 0.f;
  for (int ss = 0; ss < 64; ++ss) s += emb[b * 65536 + ss * 1024 + d];
  xmean[idx] = s * (1.f / 64.f);
}

__global__ __launch_bounds__(256) void temp_kernel(
    const float* __restrict__ emb, const float* __restrict__ tw,
    const float* __restrict__ tb, float* __restrict__ tempv) {
  __shared__ float red[4];
  int b = blockIdx.x;
  int wid = threadIdx.x >> 6, lane = threadIdx.x & 63;
  float acc = 0.f;
  for (int s = wid; s < 64; s += 4) {
    const float* x = emb + b * 65536 + s * 1024;
    float p = 0.f;
#pragma unroll
    for (int it = 0; it < 4; ++it) {
      float4 xv = *(const float4*)(x + it * 256 + lane * 4);
      float4 wv = *(const float4*)(tw + it * 256 + lane * 4);
      p += xv.x * wv.x + xv.y * wv.y + xv.z * wv.z + xv.w * wv.w;
    }
    p = wave_sum(p);
    acc += 1.f / (1.f + expf(-(p + tb[0])));
  }
  if (lane == 0) red[wid] = acc;
  __syncthreads();
  if (threadIdx.x == 0)
    tempv[b] = (red[0] + red[1] + red[2] + red[3]) * (1.f / 64.f);
}

__global__ __launch_bounds__(256) void style_kernel(
    const float* __restrict__ xmean, const float* __restrict__ sw,
    const float* __restrict__ sb, float* __restrict__ stylev) {
  int wid = threadIdx.x >> 6, lane = threadIdx.x & 63;
  int d = blockIdx.x * 4 + wid;
  const float* wr = sw + (long long)d * 1024;
  float a0 = 0.f, a1 = 0.f;
#pragma unroll
  for (int it = 0; it < 4; ++it) {
    float4 wv = *(const float4*)(wr + it * 256 + lane * 4);
    float4 x0 = *(const float4*)(xmean + it * 256 + lane * 4);
    float4 x1 = *(const float4*)(xmean + 1024 + it * 256 + lane * 4);
    a0 += wv.x * x0.x + wv.y * x0.y + wv.z * x0.z + wv.w * x0.w;
    a1 += wv.x * x1.x + wv.y * x1.y + wv.z * x1.z + wv.w * x1.w;
  }
  a0 = wave_sum(a0);
  a1 = wave_sum(a1);
  if (lane == 0) {
    stylev[d] = a0 + sb[d];
    stylev[1024 + d] = a1 + sb[d];
  }
}

// -------- logits (z computed inline): one wave per vocab row ----------
__global__ __launch_bounds__(256) void logits_kernel(
    const float* __restrict__ A, const float* __restrict__ stylev, int St,
    const float* __restrict__ Wo, const float* __restrict__ bo,
    const float* __restrict__ tempv, float* __restrict__ outl, int t) {
  int wid = threadIdx.x >> 6, lane = threadIdx.x & 63;
  int n = blockIdx.x * 4 + wid;
  const float* wr = Wo + (long long)n * 1024;
  const float* a0p = A + (long long)(St - 1) * 1024;
  const float* a1p = A + 73728 + (long long)(St - 1) * 1024;
  float a0 = 0.f, a1 = 0.f;
#pragma unroll
  for (int it = 0; it < 4; ++it) {
    int off = it * 256 + lane * 4;
    float4 wv = *(const float4*)(wr + off);
    float4 x0 = *(const float4*)(a0p + off);
    float4 s0 = *(const float4*)(stylev + off);
    float4 x1 = *(const float4*)(a1p + off);
    float4 s1 = *(const float4*)(stylev + 1024 + off);
    float4 z0 = make_float4(x0.x + s0.x, x0.y + s0.y, x0.z + s0.z, x0.w + s0.w);
    float4 z1 = make_float4(x1.x + s1.x, x1.y + s1.y, x1.z + s1.z, x1.w + s1.w);
    a0 += wv.x * z0.x + wv.y * z0.y + wv.z * z0.z + wv.w * z0.w;
    a1 += wv.x * z1.x + wv.y * z1.y + wv.z * z1.z + wv.w * z1.w;
  }
  a0 = wave_sum(a0);
  a1 = wave_sum(a1);
  if (lane == 0) {
    float bb = bo[n];
    outl[(long long)(0 * 8 + t) * 32000 + n] = (a0 + bb) / tempv[0];
    outl[(long long)(1 * 8 + t) * 32000 + n] = (a1 + bb) / tempv[1];
  }
}

// -------- Gumbel argmax sampling (partitionable threefry) + append ---------
__global__ __launch_bounds__(1024) void sample_kernel(
    const float* __restrict__ logits, const float* __restrict__ Wo,
    float* __restrict__ tok_f, float* __restrict__ cur, int St,
    uint32_t fk0, uint32_t fk1, int t) {
  int b = blockIdx.x;
  const float* lg = logits + (long long)(b * 8 + t) * 32000;
  float best = -3.4e38f;
  int bi = 0x7fffffff;
  for (int n = threadIdx.x; n < 32000; n += 1024) {
    uint32_t r0, r1;
    threefry2x32(fk0, fk1, 0u, (uint32_t)(b * 32000 + n), &r0, &r1);
    uint32_t bits = (r0 ^ r1) >> 9;
    float u = __uint_as_float(0x3f800000u | bits) - 1.0f;
    if (u < 1.1754944e-38f) u = 1.1754944e-38f;
    float g = -logf(-logf(u));
    float val = lg[n] + g;
    if (val > best) { best = val; bi = n; }
  }
  __shared__ float bv[1024];
  __shared__ int bix[1024];
  bv[threadIdx.x] = best;
  bix[threadIdx.x] = bi;
  __syncthreads();
  for (int s = 512; s > 0; s >>= 1) {
    if (threadIdx.x < s) {
      float ov = bv[threadIdx.x + s];
      int oi = bix[threadIdx.x + s];
      if (ov > bv[threadIdx.x] ||
          (ov == bv[threadIdx.x] && oi < bix[threadIdx.x])) {
        bv[threadIdx.x] = ov;
        bix[threadIdx.x] = oi;
      }
    }
    __syncthreads();
  }
  int tok = bix[0];
  if (threadIdx.x == 0) tok_f[b * 8 + t] = (float)tok;
  cur[(long long)b * 73728 + (long long)St * 1024 + threadIdx.x] =
      Wo[(long long)tok * 1024 + threadIdx.x];
}

// ---------------- host helpers ----------------
static inline void g2(hipStream_t st, const float* X, long long xbs, int ldx,
                      const float* W, int ldw, const float* bias, float* out,
                      long long obs, int ldo, int St, int M, int N, int K,
                      int splits, int relu, int partial) {
  dim3 grid((unsigned)((M + 63) / 64), (unsigned)(N / 64), (unsigned)splits);
  gemm2_kernel<<<grid, 256, 0, st>>>(X, xbs, ldx, W, ldw, bias, out, obs, ldo,
                                     St, M, N, K / (32 * splits), relu,
                                     partial);
}

static inline void epi(hipStream_t st, const float* P, int splits, int M,
                       int N, const float* bias, const float* res,
                       long long rbs, int ldr, const float* lnw,
                       const float* lnb, float* out, long long obs, int ldo,
                       int St, int relu) {
  dim3 grid((unsigned)M, (unsigned)(N / 1024));
  epi_kernel<<<grid, 256, 0, st>>>(P, splits, M, N, bias, res, rbs, ldr, lnw,
                                   lnb, out, obs, ldo, St, relu);
}

extern "C" void kernel_launch(void* const* d_in, const int* in_sizes, int n_in,
                              void* d_out, int out_size, void* d_ws,
                              size_t ws_size, hipStream_t stream) {
  const float* emb = (const float*)d_in[0];
  const float* sa_in_w = (const float*)d_in[1];
  const float* sa_in_b = (const float*)d_in[2];
  const float* sa_out_w = (const float*)d_in[3];
  const float* sa_out_b = (const float*)d_in[4];
  const float* ca_in_w = (const float*)d_in[5];
  const float* ca_in_b = (const float*)d_in[6];
  const float* ca_out_w = (const float*)d_in[7];
  const float* ca_out_b = (const float*)d_in[8];
  const float* ff1_w = (const float*)d_in[9];
  const float* ff1_b = (const float*)d_in[10];
  const float* ff2_w = (const float*)d_in[11];
  const float* ff2_b = (const float*)d_in[12];
  const float* ln_w = (const float*)d_in[13];
  const float* ln_b = (const float*)d_in[14];
  const float* out_w = (const float*)d_in[15];
  const float* out_b = (const float*)d_in[16];
  const float* temp_w = (const float*)d_in[17];
  const float* temp_b = (const float*)d_in[18];
  const float* style_w = (const float*)d_in[21];
  const float* style_b = (const float*)d_in[22];

  float* ws = (float*)d_ws;
  float* cur = ws;                       // [2][72][1024]
  float* A = cur + 2 * 72 * 1024;        // [2][72][1024]
  float* Qb = A + 2 * 72 * 1024;         // [2][72][3072]
  float* Tb = Qb + 2 * 72 * 3072;        // [2][72][1024]
  float* Fb = Tb + 2 * 72 * 1024;        // [2][72][4096]
  float* cakv = Fb + 2 * 72 * 4096;      // [2][2][64][2048]
  float* Pp = cakv + 2 * 2 * 64 * 2048;  // split-K partials (<=2.4M floats)
  float* xmean = Pp + 2400000;
  float* stylev = xmean + 2048;
  float* tempv = stylev + 2048;

  float* toks_out = (float*)d_out;
  float* logits_out = toks_out + 16;

  // ---- precompute ----
  copy_cur_kernel<<<512, 256, 0, stream>>>(emb, cur);
  xmean_kernel<<<8, 256, 0, stream>>>(emb, xmean);
  temp_kernel<<<2, 256, 0, stream>>>(emb, temp_w, temp_b, tempv);
  style_kernel<<<256, 256, 0, stream>>>(xmean, style_w, style_b, stylev);
  for (int l = 0; l < 2; ++l) {  // cross-attn K,V (memory is constant)
    g2(stream, emb, 64 * 1024, 1024,
       ca_in_w + (size_t)(l * 3072 + 1024) * 1024, 1024,
       ca_in_b + l * 3072 + 1024, cakv + (size_t)l * 2 * 64 * 2048, 64 * 2048,
       2048, 64, 128, 2048, 1024, 1, 0, 0);
  }

  for (int t = 0; t < 8; ++t) {
    int St = 64 + t;
    int M = 2 * St;
    for (int l = 0; l < 2; ++l) {
      const float* P0 = (l == 0) ? cur : A;
      // self-attn QKV: split-K x4 (576 blocks) -> epi bias
      g2(stream, P0, 72 * 1024, 1024, sa_in_w + (size_t)l * 3072 * 1024, 1024,
         nullptr, Pp, 0, 3072, St, M, 3072, 1024, 4, 0, 1);
      epi(stream, Pp, 4, M, 3072, sa_in_b + l * 3072, nullptr, 0, 0, nullptr,
          nullptr, Qb, 72 * 3072, 3072, St, 0);
      attn_kernel<<<2 * 8 * St, 64, 0, stream>>>(
          Qb, 3072, 72 * 3072, 0, 1, nullptr, Qb + 1024, 3072, 72 * 3072,
          Qb + 2048, 3072, 72 * 3072, Tb, 1024, 72 * 1024, St, St);
      // out-proj: split-K x8 (384 blocks) -> epi bias+res+LN0
      g2(stream, Tb, 72 * 1024, 1024, sa_out_w + (size_t)l * 1024 * 1024, 1024,
         nullptr, Pp, 0, 1024, St, M, 1024, 1024, 8, 0, 1);
      epi(stream, Pp, 8, M, 1024, sa_out_b + l * 1024, P0, 72 * 1024, 1024,
          ln_w + (l * 3 + 0) * 1024, ln_b + (l * 3 + 0) * 1024, A, 72 * 1024,
          1024, St, 0);
      // cross-attn Q: split-K x4 (192 blocks), partials summed inside attn
      g2(stream, A, 72 * 1024, 1024, ca_in_w + (size_t)l * 3072 * 1024, 1024,
         nullptr, Pp, 0, 1024, St, M, 1024, 1024, 4, 0, 1);
      attn_kernel<<<2 * 8 * St, 64, 0, stream>>>(
          Pp, 1024, (long long)St * 1024, (long long)M * 1024, 4,
          ca_in_b + l * 3072, cakv + (size_t)l * 2 * 64 * 2048, 2048,
          64 * 2048, cakv + (size_t)l * 2 * 64 * 2048 + 1024, 2048, 64 * 2048,
          Tb, 1024, 72 * 1024, St, 64);
      // ca out-proj: split-K x8 -> epi bias+res+LN1
      g2(stream, Tb, 72 * 1024, 1024, ca_out_w + (size_t)l * 1024 * 1024, 1024,
         nullptr, Pp, 0, 1024, St, M, 1024, 1024, 8, 0, 1);
      epi(stream, Pp, 8, M, 1024, ca_out_b + l * 1024, A, 72 * 1024, 1024,
          ln_w + (l * 3 + 1) * 1024, ln_b + (l * 3 + 1) * 1024, A, 72 * 1024,
          1024, St, 0);
      // FFN1: split-K x4 (768 blocks) -> epi bias+relu
      g2(stream, A, 72 * 1024, 1024, ff1_w + (size_t)l * 4096 * 1024, 1024,
         nullptr, Pp, 0, 4096, St, M, 4096, 1024, 4, 0, 1);
      epi(stream, Pp, 4, M, 4096, ff1_b + l * 4096, nullptr, 0, 0, nullptr,
          nullptr, Fb, 72 * 4096, 4096, St, 1);
      // FFN2: split-K x16 (768 blocks) -> epi bias+res+LN2
      g2(stream, Fb, 72 * 4096, 4096, ff2_w + (size_t)l * 1024 * 4096, 4096,
         nullptr, Pp, 0, 1024, St, M, 1024, 4096, 16, 0, 1);
      epi(stream, Pp, 16, M, 1024, ff2_b + l * 1024, A, 72 * 1024, 1024,
          ln_w + (l * 3 + 2) * 1024, ln_b + (l * 3 + 2) * 1024, A, 72 * 1024,
          1024, St, 0);
    }
    logits_kernel<<<8000, 256, 0, stream>>>(A, stylev, St, out_w, out_b,
                                            tempv, logits_out, t);
    uint32_t fk0, fk1;
    threefry2x32(0u, 42u, 0u, (uint32_t)t, &fk0, &fk1);
    sample_kernel<<<2, 1024, 0, stream>>>(logits_out, out_w, toks_out, cur,
                                          St, fk0, fk1, t);
  }
}